// Round 16
// baseline (190.876 us; speedup 1.0000x reference)
//
#include <hip/hip_runtime.h>
#include <cstdint>
#include <cstddef>

#define TOKENS 16384
#define DIM    2048
#define NEXP   8
#define RANK   128
#define NOUT   2048
#define CAP    8192   // per-pair-bin token capacity (avg ~585, 14x headroom)
#define KSL    4      // logits K-slices (512 wide each) -- R11-proven config

typedef __attribute__((ext_vector_type(4))) float    f32x4;
typedef __attribute__((ext_vector_type(8))) _Float16 f16x8;
typedef __attribute__((ext_vector_type(4))) _Float16 f16x4;

// ---------------------------------------------------------------- utilities
__device__ __forceinline__ void gload_lds16(const void* g, void* l) {
  __builtin_amdgcn_global_load_lds(
      (const __attribute__((address_space(1))) void*)g,
      (__attribute__((address_space(3))) void*)l, 16, 0, 0);
}

// ------------------------------------------------- transpose + cast to f16
// in: [E][R][C] fp32.  out element: out[e*obase + c*ostride + r] = in[e][r][c]
__global__ __launch_bounds__(256) void transpose_cast_f16(
    const float* __restrict__ in, _Float16* __restrict__ out,
    int R, int C, long ostride, long obase)
{
  __shared__ float tile[32][33];
  const int e = blockIdx.z;
  const float* ine = in + (size_t)e * R * C;
  const int c0 = blockIdx.x * 32, r0 = blockIdx.y * 32;
  const int tx = threadIdx.x, ty = threadIdx.y;
#pragma unroll
  for (int j = 0; j < 32; j += 8)
    tile[ty + j][tx] = ine[(size_t)(r0 + ty + j) * C + (c0 + tx)];
  __syncthreads();
#pragma unroll
  for (int j = 0; j < 32; j += 8)
    out[(size_t)e * obase + (size_t)(c0 + ty + j) * ostride + (r0 + tx)] =
        (_Float16)tile[tx][ty + j];
}

// ------------------------------------------------------------ logits_fused
// R11-proven: 64KB LDS, 512-wide K slices, A staged via gload_lds into
// XOR-swizzled [128][256B] fp32 tile; rw split-cast (double-f16) in LDS.
// Also zeroes counts[64] from block (0,0).
__global__ __launch_bounds__(256) void logits_fused_kernel(
    const float* __restrict__ x, const float* __restrict__ rw,
    float* __restrict__ lgpart, float* __restrict__ ssqpart,
    _Float16* __restrict__ xh, int* __restrict__ counts)
{
  __shared__ __align__(16) char lds[65536];
  char* ldsA  = lds;           // [128 rows][256B fp32], swizzled
  char* ldsBh = lds + 32768;   // [16][1024B f16] hi (rows 8..15 zero)
  char* ldsBe = lds + 49152;   // [16][1024B f16] lo
  const int tid = threadIdx.x;
  const int w = tid >> 6, l = tid & 63;
  const int m0 = blockIdx.x * 128;
  const int ks = blockIdx.y;            // K-slice, 512 wide
  const int kbase = ks * 512;

  if (blockIdx.x == 0 && ks == 0 && tid < 64) counts[tid] = 0;

  // split-cast rw slice -> (ldsBh, ldsBe), byte ^= ((n&7)<<4); rows 8..15 = 0
#pragma unroll
  for (int i = 0; i < 32; ++i) {
    const int idx = tid * 32 + i;       // 0..8191 over [16][512]
    const int n = idx >> 9, k = idx & 511;
    const float v = (n < 8) ? rw[(size_t)(kbase + k) * 8 + n] : 0.f;
    const _Float16 h = (_Float16)v;
    const _Float16 e = (_Float16)(v - (float)h);
    const int off = n * 1024 + ((k * 2) ^ ((n & 7) << 4));
    *(_Float16*)(ldsBh + off) = h;
    *(_Float16*)(ldsBe + off) = e;
  }

  const int Lb = w * 1024 + l * 16;
  const float* agp[8];
  int ldst[8];
#pragma unroll
  for (int i = 0; i < 8; ++i) {
    const int L = i * 4096 + Lb;
    const int row = L >> 8;                       // 256B fp32 rows
    const int cb = (L & 255) ^ ((row & 7) << 4);
    agp[i] = x + (size_t)(m0 + row) * DIM + kbase + (cb >> 2);
    ldst[i] = i * 4096 + w * 1024;
  }

  f32x4 acc[2];
  float ssl[2] = {0.f, 0.f};
#pragma unroll
  for (int mf = 0; mf < 2; ++mf)
#pragma unroll
    for (int j = 0; j < 4; ++j) acc[mf][j] = 0.f;

  for (int st = 0; st < 8; ++st) {
#pragma unroll
    for (int i = 0; i < 8; ++i)
      gload_lds16(agp[i] + st * 64, ldsA + ldst[i]);
    __syncthreads();                     // covers B writes on st==0 too
#pragma unroll
    for (int kk = 0; kk < 2; ++kk) {
      const int n = l & 15;
      const int bko = n * 1024 +
          ((st * 128 + kk * 64 + ((l >> 4) << 4)) ^ ((n & 7) << 4));
      const f16x8 bh = *(const f16x8*)(ldsBh + bko);
      const f16x8 be = *(const f16x8*)(ldsBe + bko);
#pragma unroll
      for (int mf = 0; mf < 2; ++mf) {
        const int r = w * 32 + mf * 16 + (l & 15);
        const int s = (r & 7) << 4;
        const int c0 = kk * 128 + ((l >> 4) << 5);
        const f32x4 va = *(const f32x4*)(ldsA + r * 256 + ((c0) ^ s));
        const f32x4 vb = *(const f32x4*)(ldsA + r * 256 + ((c0 + 16) ^ s));
        float f[8] = {va[0], va[1], va[2], va[3], vb[0], vb[1], vb[2], vb[3]};
        f16x8 ah, ae;
#pragma unroll
        for (int j = 0; j < 8; ++j) {
          ah[j] = (_Float16)f[j];
          ae[j] = (_Float16)(f[j] - (float)ah[j]);
          ssl[mf] = fmaf(f[j], f[j], ssl[mf]);
        }
        // xh = f16(x): fragment covers 8 contiguous cols of row m0+r
        *(f16x8*)(xh + (size_t)(m0 + r) * DIM + kbase + st * 64 + kk * 32 +
                  ((l >> 4) << 3)) = ah;
        acc[mf] = __builtin_amdgcn_mfma_f32_16x16x32_f16(ae, bh, acc[mf], 0, 0, 0);
        acc[mf] = __builtin_amdgcn_mfma_f32_16x16x32_f16(ah, be, acc[mf], 0, 0, 0);
        acc[mf] = __builtin_amdgcn_mfma_f32_16x16x32_f16(ah, bh, acc[mf], 0, 0, 0);
      }
    }
    __syncthreads();
  }

  // lgpart: C/D layout col = lane&15, row = (lane>>4)*4 + j
  const int col = l & 15;
  if (col < 8) {
#pragma unroll
    for (int mf = 0; mf < 2; ++mf) {
      const int rbase = m0 + w * 32 + mf * 16 + ((l >> 4) << 2);
#pragma unroll
      for (int j = 0; j < 4; ++j)
        lgpart[((size_t)ks * TOKENS + rbase + j) * 8 + col] = acc[mf][j];
    }
  }
  // ssqpart: lane's ssl[mf] covers 128 cols of row w*32+mf*16+(l&15)
#pragma unroll
  for (int mf = 0; mf < 2; ++mf) {
    float s = ssl[mf];
    s += __shfl_xor(s, 16, 64);
    s += __shfl_xor(s, 32, 64);
    if (l < 16)
      ssqpart[(size_t)ks * TOKENS + m0 + w * 32 + mf * 16 + l] = s;
  }
}

// ------------------------------------------------------------ softmax_top2
// combine[t][e]; bins token t into pair bin a*8+b (a<b). Bin order is
// nondeterministic (atomicAdd) but each token's output value is
// order-independent -> deterministic result.
__global__ __launch_bounds__(256) void softmax_top2_kernel(
    const float* __restrict__ lgpart, const float* __restrict__ ssqpart,
    float* __restrict__ combine, int* __restrict__ counts,
    unsigned short* __restrict__ ids16)
{
  const size_t t = (size_t)blockIdx.x * 256 + threadIdx.x;
  float ss = 0.f;
  float lg[8];
#pragma unroll
  for (int e = 0; e < 8; ++e) lg[e] = 0.f;
#pragma unroll
  for (int ks = 0; ks < KSL; ++ks) {
    ss += ssqpart[(size_t)ks * TOKENS + t];
    const float* p = lgpart + ((size_t)ks * TOKENS + t) * 8;
    float4 a = *(const float4*)(p);
    float4 b = *(const float4*)(p + 4);
    lg[0] += a.x; lg[1] += a.y; lg[2] += a.z; lg[3] += a.w;
    lg[4] += b.x; lg[5] += b.y; lg[6] += b.z; lg[7] += b.w;
  }
  const float iv = 1.f / fmaxf(sqrtf(ss), 1e-12f);
#pragma unroll
  for (int e = 0; e < 8; ++e) lg[e] *= iv;
  float b1 = lg[0]; int e1 = 0;
#pragma unroll
  for (int e = 1; e < 8; ++e)
    if (lg[e] > b1) { b1 = lg[e]; e1 = e; }
  float b2 = -3.4e38f; int e2 = 0;
#pragma unroll
  for (int e = 0; e < 8; ++e)
    if (e != e1 && lg[e] > b2) { b2 = lg[e]; e2 = e; }
  const float p2 = expf(b2 - b1);
  const float w1 = 1.f / (1.f + p2);
  const float w2 = p2 * w1;
  float ov[8];
#pragma unroll
  for (int e = 0; e < 8; ++e)
    ov[e] = (e == e1) ? w1 : ((e == e2) ? w2 : 0.f);
  float4* cp = (float4*)(combine + t * 8);
  cp[0] = make_float4(ov[0], ov[1], ov[2], ov[3]);
  cp[1] = make_float4(ov[4], ov[5], ov[6], ov[7]);

  const int a = min(e1, e2), b = max(e1, e2);
  const int bin = a * 8 + b;
  const int pos = atomicAdd(&counts[bin], 1);
  if (pos < CAP) ids16[bin * CAP + pos] = (unsigned short)t;
}

// -------------------------------------------------------------- make_items
// Wave-parallel builder of two work lists: 32-row tiles for gemm1 (<=576)
// and 128-row tiles for gemm2 (<=192). Lane b owns bin b.
__global__ void make_items_kernel(const int* __restrict__ counts,
                                  int4* __restrict__ items32,
                                  int4* __restrict__ items128)
{
  const int l = threadIdx.x;            // 64 lanes, one per bin
  const int c = min(counts[l], CAP);
  const int n32 = (c + 31) >> 5;
  const int n128 = (c + 127) >> 7;
  int p32 = n32, p128 = n128;           // inclusive prefix sums
#pragma unroll
  for (int m = 1; m < 64; m <<= 1) {
    int u = __shfl_up(p32, m, 64);  if (l >= m) p32 += u;
    int v = __shfl_up(p128, m, 64); if (l >= m) p128 += v;
  }
  const int tot32 = __shfl(p32, 63, 64);
  const int tot128 = __shfl(p128, 63, 64);
  int j = p32 - n32;
  for (int s = 0; s < c; s += 32, ++j)
    items32[j] = make_int4(l, l * CAP + s, min(32, c - s), 0);
  j = p128 - n128;
  for (int s = 0; s < c; s += 128, ++j)
    items128[j] = make_int4(l, l * CAP + s, min(128, c - s), 0);
  for (int k = tot32 + l; k < 576; k += 64) items32[k] = make_int4(-1, 0, 0, 0);
  for (int k = tot128 + l; k < 192; k += 64) items128[k] = make_int4(-1, 0, 0, 0);
}

// -------------------------------------------------------------- gemm1_pair
// Grouped by pair bin, BM=32 tiles, BOTH experts per block (N=256):
// halves the gathered xh traffic vs slot-split. Grid 576 (~2.25/CU,
// 4 resident at 36.2KB LDS). Wave w owns n-range w*64; waves 0-1 ->
// expert a (slot 0), waves 2-3 -> expert b (slot 1). 16 MFMA/wave/step.
// Yc[t][slot*128+r] = combine[t][e_slot] * (xh[t] . WaT[e_slot*128+r]).
__global__ __launch_bounds__(256) void gemm1_pair_kernel(
    const _Float16* __restrict__ xh, const _Float16* __restrict__ WaT,
    const float* __restrict__ combine, const unsigned short* __restrict__ ids,
    const int4* __restrict__ items, _Float16* __restrict__ Yc)
{
  __shared__ __align__(16) char lds[36864];
  __shared__ int ids_lds[32];
  char* ldsA = lds;              // [32 rows][128B]
  char* ldsB = lds + 4096;       // [256 rows][128B]: 0..127 expert a,
                                 //                   128..255 expert b
  const int4 item = items[blockIdx.x];
  if (item.x < 0) return;                 // block-uniform exit
  const int ea = item.x >> 3, eb = item.x & 7;
  const int tid = threadIdx.x;
  const int w = tid >> 6, l = tid & 63;

  if (tid < 32)
    ids_lds[tid] = (tid < item.z) ? (int)ids[item.y + tid] : -1;
  __syncthreads();

  // A staging: 4KB/step, thread tid -> row tid>>3 (0..31)
  const int arow = tid >> 3;
  const int acb = (((tid & 7) << 4) ^ ((arow & 7) << 4));
  int ta = ids_lds[arow]; if (ta < 0) ta = 0;     // pad rows read token 0
  const _Float16* aptr = xh + (size_t)ta * DIM + (acb >> 1);
  const int aoff = tid * 16;                       // linear dest

  // B staging: 32KB/step, 8 chunks; row = L>>7 (0..255)
  const _Float16* bptr[8];
  int boff[8];
#pragma unroll
  for (int i = 0; i < 8; ++i) {
    const int L = i * 4096 + tid * 16;
    const int row = L >> 7;
    const int cb = (L & 127) ^ ((row & 7) << 4);
    const int e = (row < 128) ? ea : eb;
    bptr[i] = WaT + (size_t)(e * 128 + (row & 127)) * DIM + (cb >> 1);
    boff[i] = L;
  }

  f32x4 acc[2][4];
#pragma unroll
  for (int p = 0; p < 2; ++p)
#pragma unroll
    for (int q = 0; q < 4; ++q)
#pragma unroll
      for (int j = 0; j < 4; ++j) acc[p][q][j] = 0.f;

  for (int kt = 0; kt < DIM; kt += 64) {
    gload_lds16(aptr + kt, ldsA + aoff);
#pragma unroll
    for (int i = 0; i < 8; ++i)
      gload_lds16(bptr[i] + kt, ldsB + boff[i]);
    __syncthreads();
#pragma unroll
    for (int kk = 0; kk < 2; ++kk) {
      const int kb = kk * 64 + ((l >> 4) << 4);
      f16x8 af[2], bfr[4];
#pragma unroll
      for (int mf = 0; mf < 2; ++mf) {
        const int r = (mf << 4) + (l & 15);
        af[mf] = *(const f16x8*)(ldsA + r * 128 + (kb ^ ((r & 7) << 4)));
      }
#pragma unroll
      for (int nf = 0; nf < 4; ++nf) {
        const int r = (w << 6) + (nf << 4) + (l & 15);
        bfr[nf] = *(const f16x8*)(ldsB + r * 128 + (kb ^ ((r & 7) << 4)));
      }
#pragma unroll
      for (int mf = 0; mf < 2; ++mf)
#pragma unroll
        for (int nf = 0; nf < 4; ++nf)
          acc[mf][nf] = __builtin_amdgcn_mfma_f32_16x16x32_f16(
              af[mf], bfr[nf], acc[mf][nf], 0, 0, 0);
    }
    __syncthreads();
  }

  // epilogue: wave w -> slot w>>1, expert (w<2?ea:eb), n-base (w&1)*64
  const int e_sel = (w < 2) ? ea : eb;
  const int slot = w >> 1;
  const int cr = (l >> 4) << 2;
  const int cc = l & 15;
#pragma unroll
  for (int mf = 0; mf < 2; ++mf) {
    const int lr0 = (mf << 4) + cr;
#pragma unroll
    for (int j = 0; j < 4; ++j) {
      const int t = ids_lds[lr0 + j];
      if (t < 0) continue;
      const float cs = combine[(size_t)t * 8 + e_sel];
      _Float16* yr = Yc + (size_t)t * 256 + slot * 128 + ((w & 1) << 6);
#pragma unroll
      for (int nf = 0; nf < 4; ++nf)
        yr[(nf << 4) + cc] = (_Float16)(acc[mf][nf][j] * cs);
    }
  }
}

// -------------------------------------------------------------- gemm2_pair
// out[t] = Yc[t][0:256] @ [Wb_a; Wb_b] for tokens in this tile's pair bin.
__global__ __launch_bounds__(256) void gemm2_pair_kernel(
    const _Float16* __restrict__ Y, const _Float16* __restrict__ WbT,
    const unsigned short* __restrict__ ids, const int4* __restrict__ items,
    float* __restrict__ out)
{
  __shared__ __align__(16) char lds[32768];
  __shared__ int ids_lds[128];
  char* ldsA = lds;
  char* ldsB = lds + 16384;
  const int4 item = items[blockIdx.y];
  if (item.x < 0) return;                 // block-uniform exit
  const int a = item.x >> 3, b = item.x & 7;
  const int n0 = blockIdx.x * 128;
  const int tid = threadIdx.x;
  const int w = tid >> 6, l = tid & 63;
  const int wm = w >> 1, wn = w & 1;

  if (tid < 128)
    ids_lds[tid] = (tid < item.z) ? (int)ids[item.y + tid] : -1;
  __syncthreads();

  const int Lb = w * 1024 + l * 16;
  const _Float16* aptr[4];
  const _Float16* bptrA[4];
  const _Float16* bptrB[4];
  int ldst[4];
#pragma unroll
  for (int i = 0; i < 4; ++i) {
    const int L = i * 4096 + Lb;
    const int row = L >> 7;
    const int cb = (L & 127) ^ ((row & 7) << 4);
    int t = ids_lds[row]; if (t < 0) t = 0;       // pad rows read token 0
    aptr[i]  = Y + (size_t)t * 256 + (cb >> 1);
    bptrA[i] = WbT + (size_t)(n0 + row) * 1024 + a * 128 + (cb >> 1);
    bptrB[i] = WbT + (size_t)(n0 + row) * 1024 + b * 128 + (cb >> 1);
    ldst[i] = i * 4096 + w * 1024;
  }

  f32x4 acc[4][4];
#pragma unroll
  for (int p = 0; p < 4; ++p)
#pragma unroll
    for (int q = 0; q < 4; ++q)
#pragma unroll
      for (int j = 0; j < 4; ++j) acc[p][q][j] = 0.f;

#pragma unroll
  for (int kt = 0; kt < 4; ++kt) {
#pragma unroll
    for (int i = 0; i < 4; ++i) {
      gload_lds16(aptr[i] + kt * 64, ldsA + ldst[i]);
      const _Float16* bs = (kt < 2) ? (bptrA[i] + kt * 64)
                                    : (bptrB[i] + (kt - 2) * 64);
      gload_lds16(bs, ldsB + ldst[i]);
    }
    __syncthreads();
#pragma unroll
    for (int kk = 0; kk < 2; ++kk) {
      const int kb = kk * 64 + ((l >> 4) << 4);
      f16x8 af[4], bfr[4];
#pragma unroll
      for (int mf = 0; mf < 4; ++mf) {
        const int r = (wm << 6) + (mf << 4) + (l & 15);
        af[mf] = *(const f16x8*)(ldsA + r * 128 + (kb ^ ((r & 7) << 4)));
      }
#pragma unroll
      for (int nf = 0; nf < 4; ++nf) {
        const int r = (wn << 6) + (nf << 4) + (l & 15);
        bfr[nf] = *(const f16x8*)(ldsB + r * 128 + (kb ^ ((r & 7) << 4)));
      }
#pragma unroll
      for (int mf = 0; mf < 4; ++mf)
#pragma unroll
        for (int nf = 0; nf < 4; ++nf)
          acc[mf][nf] = __builtin_amdgcn_mfma_f32_16x16x32_f16(
              af[mf], bfr[nf], acc[mf][nf], 0, 0, 0);
    }
    __syncthreads();
  }

  // epilogue: scatter rows to out[token]
  const int cr = (l >> 4) << 2;
  const int cc = l & 15;
#pragma unroll
  for (int mf = 0; mf < 4; ++mf) {
    const int lr0 = (wm << 6) + (mf << 4) + cr;
#pragma unroll
    for (int j = 0; j < 4; ++j) {
      const int t = ids_lds[lr0 + j];
      if (t < 0) continue;
      float* orow = out + (size_t)t * NOUT + n0;
#pragma unroll
      for (int nf = 0; nf < 4; ++nf)
        orow[(wn << 6) + (nf << 4) + cc] = acc[mf][nf][j];
    }
  }
}

// ------------------------------------------------------------------ launch
extern "C" void kernel_launch(void* const* d_in, const int* in_sizes, int n_in,
                              void* d_out, int out_size, void* d_ws, size_t ws_size,
                              hipStream_t stream) {
  const float* x  = (const float*)d_in[0];   // [4,4096,2048]
  const float* rw = (const float*)d_in[1];   // [2048,8]
  const float* Wa = (const float*)d_in[2];   // [8,2048,128]
  const float* Wb = (const float*)d_in[3];   // [8,128,2048]
  float* out = (float*)d_out;                // [4,4096,2048]

  char* ws = (char*)d_ws;
  // workspace layout (total ~85.5 MB)
  _Float16* xh       = (_Float16*)(ws);                // 67,108,864 [T][2048]
  _Float16* WaT      = (_Float16*)(ws + 67108864);     //  4,194,304 [1024][2048]
  _Float16* WbT      = (_Float16*)(ws + 71303168);     //  4,194,304 [2048][1024]
  float*    combine  = (float*)   (ws + 75497472);     //    524,288 [T][8]
  int*      counts   = (int*)     (ws + 76021760);     //        256 [64]
  int4*     items32  = (int4*)    (ws + 76022016);     //      9,216 [576]
  int4*     items128 = (int4*)    (ws + 76031232);     //      3,072 [192]
  unsigned short* ids16 = (unsigned short*)(ws + 76034304); // 1,048,576 [64][CAP]
  _Float16* Yc       = (_Float16*)(ws + 77082880);     //  8,388,608 [T][256]
  float*    lgpart   = (float*)   (ws + 77082880);     // 2 MB [KSL][T][8], aliases Yc
  float*    ssqpart  = (float*)   (ws + 79180032);     // 256 KB [KSL][T], aliases Yc
  // (lgpart/ssqpart consumed by softmax before gemm1_pair writes Yc)

  // WaT[(e*128+r)][k] = Wa[e][k][r]
  transpose_cast_f16<<<dim3(4, 64, 8), dim3(32, 8), 0, stream>>>(
      Wa, WaT, 2048, 128, 2048, (long)128 * 2048);
  // WbT[n][e*128+r] = Wb[e][r][n]
  transpose_cast_f16<<<dim3(64, 4, 8), dim3(32, 8), 0, stream>>>(
      Wb, WbT, 128, 2048, 1024, 128);

  // also zeroes counts[] (block (0,0)) -- no separate memset node
  logits_fused_kernel<<<dim3(TOKENS / 128, KSL), 256, 0, stream>>>(
      x, rw, lgpart, ssqpart, xh, counts);

  softmax_top2_kernel<<<TOKENS / 256, 256, 0, stream>>>(
      lgpart, ssqpart, combine, counts, ids16);
  make_items_kernel<<<1, 64, 0, stream>>>(counts, items32, items128);

  // Yc[t][slot*128+r] = combine[t][e_slot] * (xh[t] . WaT[e_slot*128+r])
  gemm1_pair_kernel<<<576, 256, 0, stream>>>(
      xh, WaT, combine, ids16, items32, Yc);
  // out[t] = Yc[t][0:256] @ [Wb_a; Wb_b]
  gemm2_pair_kernel<<<dim3(NOUT / 128, 192), 256, 0, stream>>>(
      Yc, WbT, ids16, items128, out);
}

// Round 17
// 185.793 us; speedup vs baseline: 1.0274x; 1.0274x over previous
//
#include <hip/hip_runtime.h>
#include <cstdint>
#include <cstddef>

#define TOKENS 16384
#define DIM    2048
#define NEXP   8
#define RANK   128
#define NOUT   2048
#define CAP    8192   // per-pair-bin token capacity (avg ~585, 14x headroom)
#define KSL    4      // logits K-slices (512 wide each) -- R11-proven config

typedef __attribute__((ext_vector_type(4))) float    f32x4;
typedef __attribute__((ext_vector_type(8))) _Float16 f16x8;
typedef __attribute__((ext_vector_type(4))) _Float16 f16x4;

// ---------------------------------------------------------------- utilities
__device__ __forceinline__ void gload_lds16(const void* g, void* l) {
  __builtin_amdgcn_global_load_lds(
      (const __attribute__((address_space(1))) void*)g,
      (__attribute__((address_space(3))) void*)l, 16, 0, 0);
}

// ------------------------------------------------- transpose + cast to f16
// in: [E][R][C] fp32.  out element: out[e*obase + c*ostride + r] = in[e][r][c]
__global__ __launch_bounds__(256) void transpose_cast_f16(
    const float* __restrict__ in, _Float16* __restrict__ out,
    int R, int C, long ostride, long obase)
{
  __shared__ float tile[32][33];
  const int e = blockIdx.z;
  const float* ine = in + (size_t)e * R * C;
  const int c0 = blockIdx.x * 32, r0 = blockIdx.y * 32;
  const int tx = threadIdx.x, ty = threadIdx.y;
#pragma unroll
  for (int j = 0; j < 32; j += 8)
    tile[ty + j][tx] = ine[(size_t)(r0 + ty + j) * C + (c0 + tx)];
  __syncthreads();
#pragma unroll
  for (int j = 0; j < 32; j += 8)
    out[(size_t)e * obase + (size_t)(c0 + ty + j) * ostride + (r0 + tx)] =
        (_Float16)tile[tx][ty + j];
}

// ------------------------------------------------------------ logits_fused
// R11-proven: 64KB LDS, 512-wide K slices, A staged via gload_lds into
// XOR-swizzled [128][256B] fp32 tile; rw split-cast (double-f16) in LDS.
// Also zeroes counts[64] from block (0,0).
__global__ __launch_bounds__(256) void logits_fused_kernel(
    const float* __restrict__ x, const float* __restrict__ rw,
    float* __restrict__ lgpart, float* __restrict__ ssqpart,
    _Float16* __restrict__ xh, int* __restrict__ counts)
{
  __shared__ __align__(16) char lds[65536];
  char* ldsA  = lds;           // [128 rows][256B fp32], swizzled
  char* ldsBh = lds + 32768;   // [16][1024B f16] hi (rows 8..15 zero)
  char* ldsBe = lds + 49152;   // [16][1024B f16] lo
  const int tid = threadIdx.x;
  const int w = tid >> 6, l = tid & 63;
  const int m0 = blockIdx.x * 128;
  const int ks = blockIdx.y;            // K-slice, 512 wide
  const int kbase = ks * 512;

  if (blockIdx.x == 0 && ks == 0 && tid < 64) counts[tid] = 0;

  // split-cast rw slice -> (ldsBh, ldsBe), byte ^= ((n&7)<<4); rows 8..15 = 0
#pragma unroll
  for (int i = 0; i < 32; ++i) {
    const int idx = tid * 32 + i;       // 0..8191 over [16][512]
    const int n = idx >> 9, k = idx & 511;
    const float v = (n < 8) ? rw[(size_t)(kbase + k) * 8 + n] : 0.f;
    const _Float16 h = (_Float16)v;
    const _Float16 e = (_Float16)(v - (float)h);
    const int off = n * 1024 + ((k * 2) ^ ((n & 7) << 4));
    *(_Float16*)(ldsBh + off) = h;
    *(_Float16*)(ldsBe + off) = e;
  }

  const int Lb = w * 1024 + l * 16;
  const float* agp[8];
  int ldst[8];
#pragma unroll
  for (int i = 0; i < 8; ++i) {
    const int L = i * 4096 + Lb;
    const int row = L >> 8;                       // 256B fp32 rows
    const int cb = (L & 255) ^ ((row & 7) << 4);
    agp[i] = x + (size_t)(m0 + row) * DIM + kbase + (cb >> 2);
    ldst[i] = i * 4096 + w * 1024;
  }

  f32x4 acc[2];
  float ssl[2] = {0.f, 0.f};
#pragma unroll
  for (int mf = 0; mf < 2; ++mf)
#pragma unroll
    for (int j = 0; j < 4; ++j) acc[mf][j] = 0.f;

  for (int st = 0; st < 8; ++st) {
#pragma unroll
    for (int i = 0; i < 8; ++i)
      gload_lds16(agp[i] + st * 64, ldsA + ldst[i]);
    __syncthreads();                     // covers B writes on st==0 too
#pragma unroll
    for (int kk = 0; kk < 2; ++kk) {
      const int n = l & 15;
      const int bko = n * 1024 +
          ((st * 128 + kk * 64 + ((l >> 4) << 4)) ^ ((n & 7) << 4));
      const f16x8 bh = *(const f16x8*)(ldsBh + bko);
      const f16x8 be = *(const f16x8*)(ldsBe + bko);
#pragma unroll
      for (int mf = 0; mf < 2; ++mf) {
        const int r = w * 32 + mf * 16 + (l & 15);
        const int s = (r & 7) << 4;
        const int c0 = kk * 128 + ((l >> 4) << 5);
        const f32x4 va = *(const f32x4*)(ldsA + r * 256 + ((c0) ^ s));
        const f32x4 vb = *(const f32x4*)(ldsA + r * 256 + ((c0 + 16) ^ s));
        float f[8] = {va[0], va[1], va[2], va[3], vb[0], vb[1], vb[2], vb[3]};
        f16x8 ah, ae;
#pragma unroll
        for (int j = 0; j < 8; ++j) {
          ah[j] = (_Float16)f[j];
          ae[j] = (_Float16)(f[j] - (float)ah[j]);
          ssl[mf] = fmaf(f[j], f[j], ssl[mf]);
        }
        // xh = f16(x): fragment covers 8 contiguous cols of row m0+r
        *(f16x8*)(xh + (size_t)(m0 + r) * DIM + kbase + st * 64 + kk * 32 +
                  ((l >> 4) << 3)) = ah;
        acc[mf] = __builtin_amdgcn_mfma_f32_16x16x32_f16(ae, bh, acc[mf], 0, 0, 0);
        acc[mf] = __builtin_amdgcn_mfma_f32_16x16x32_f16(ah, be, acc[mf], 0, 0, 0);
        acc[mf] = __builtin_amdgcn_mfma_f32_16x16x32_f16(ah, bh, acc[mf], 0, 0, 0);
      }
    }
    __syncthreads();
  }

  // lgpart: C/D layout col = lane&15, row = (lane>>4)*4 + j
  const int col = l & 15;
  if (col < 8) {
#pragma unroll
    for (int mf = 0; mf < 2; ++mf) {
      const int rbase = m0 + w * 32 + mf * 16 + ((l >> 4) << 2);
#pragma unroll
      for (int j = 0; j < 4; ++j)
        lgpart[((size_t)ks * TOKENS + rbase + j) * 8 + col] = acc[mf][j];
    }
  }
  // ssqpart: lane's ssl[mf] covers 128 cols of row w*32+mf*16+(l&15)
#pragma unroll
  for (int mf = 0; mf < 2; ++mf) {
    float s = ssl[mf];
    s += __shfl_xor(s, 16, 64);
    s += __shfl_xor(s, 32, 64);
    if (l < 16)
      ssqpart[(size_t)ks * TOKENS + m0 + w * 32 + mf * 16 + l] = s;
  }
}

// ------------------------------------------------------------ softmax_top2
// combine[t][e]; bins token t into pair bin a*8+b (a<b). Bin order is
// nondeterministic (atomicAdd) but each token's output value is
// order-independent -> deterministic result.
__global__ __launch_bounds__(256) void softmax_top2_kernel(
    const float* __restrict__ lgpart, const float* __restrict__ ssqpart,
    float* __restrict__ combine, int* __restrict__ counts,
    unsigned short* __restrict__ ids16)
{
  const size_t t = (size_t)blockIdx.x * 256 + threadIdx.x;
  float ss = 0.f;
  float lg[8];
#pragma unroll
  for (int e = 0; e < 8; ++e) lg[e] = 0.f;
#pragma unroll
  for (int ks = 0; ks < KSL; ++ks) {
    ss += ssqpart[(size_t)ks * TOKENS + t];
    const float* p = lgpart + ((size_t)ks * TOKENS + t) * 8;
    float4 a = *(const float4*)(p);
    float4 b = *(const float4*)(p + 4);
    lg[0] += a.x; lg[1] += a.y; lg[2] += a.z; lg[3] += a.w;
    lg[4] += b.x; lg[5] += b.y; lg[6] += b.z; lg[7] += b.w;
  }
  const float iv = 1.f / fmaxf(sqrtf(ss), 1e-12f);
#pragma unroll
  for (int e = 0; e < 8; ++e) lg[e] *= iv;
  float b1 = lg[0]; int e1 = 0;
#pragma unroll
  for (int e = 1; e < 8; ++e)
    if (lg[e] > b1) { b1 = lg[e]; e1 = e; }
  float b2 = -3.4e38f; int e2 = 0;
#pragma unroll
  for (int e = 0; e < 8; ++e)
    if (e != e1 && lg[e] > b2) { b2 = lg[e]; e2 = e; }
  const float p2 = expf(b2 - b1);
  const float w1 = 1.f / (1.f + p2);
  const float w2 = p2 * w1;
  float ov[8];
#pragma unroll
  for (int e = 0; e < 8; ++e)
    ov[e] = (e == e1) ? w1 : ((e == e2) ? w2 : 0.f);
  float4* cp = (float4*)(combine + t * 8);
  cp[0] = make_float4(ov[0], ov[1], ov[2], ov[3]);
  cp[1] = make_float4(ov[4], ov[5], ov[6], ov[7]);

  const int a = min(e1, e2), b = max(e1, e2);
  const int bin = a * 8 + b;
  const int pos = atomicAdd(&counts[bin], 1);
  if (pos < CAP) ids16[bin * CAP + pos] = (unsigned short)t;
}

// -------------------------------------------------------------- make_items
// Wave-parallel builder of two work lists: 64-row tiles for gemm1 (<=320,
// padded to 384) and 128-row tiles for gemm2 (<=192). Lane b owns bin b.
__global__ void make_items_kernel(const int* __restrict__ counts,
                                  int4* __restrict__ items64,
                                  int4* __restrict__ items128)
{
  const int l = threadIdx.x;            // 64 lanes, one per bin
  const int c = min(counts[l], CAP);
  const int n64 = (c + 63) >> 6;
  const int n128 = (c + 127) >> 7;
  int p64 = n64, p128 = n128;           // inclusive prefix sums
#pragma unroll
  for (int m = 1; m < 64; m <<= 1) {
    int u = __shfl_up(p64, m, 64);  if (l >= m) p64 += u;
    int v = __shfl_up(p128, m, 64); if (l >= m) p128 += v;
  }
  const int tot64 = __shfl(p64, 63, 64);
  const int tot128 = __shfl(p128, 63, 64);
  int j = p64 - n64;
  for (int s = 0; s < c; s += 64, ++j)
    items64[j] = make_int4(l, l * CAP + s, min(64, c - s), 0);
  j = p128 - n128;
  for (int s = 0; s < c; s += 128, ++j)
    items128[j] = make_int4(l, l * CAP + s, min(128, c - s), 0);
  for (int k = tot64 + l; k < 384; k += 64) items64[k] = make_int4(-1, 0, 0, 0);
  for (int k = tot128 + l; k < 192; k += 64) items128[k] = make_int4(-1, 0, 0, 0);
}

// -------------------------------------------------------------- gemm1_pair
// Grouped by pair bin, BM=64 tiles (768-block grid ~3/CU, halved tail):
// Yc[t][slot*128+r] = combine[t][e_slot] * (xh[t] . WaT[e*128+r]).
// K=2048 (32 BK=64 steps), A rows gathered by token id. 24.5KB LDS.
__global__ __launch_bounds__(256) void gemm1_pair_kernel(
    const _Float16* __restrict__ xh, const _Float16* __restrict__ WaT,
    const float* __restrict__ combine, const unsigned short* __restrict__ ids,
    const int4* __restrict__ items, _Float16* __restrict__ Yc)
{
  __shared__ __align__(16) char lds[24576];
  __shared__ int ids_lds[64];
  char* ldsA = lds;              // [64 rows][128B]
  char* ldsB = lds + 8192;       // [128 rows][128B]
  const int4 item = items[blockIdx.y];
  if (item.x < 0) return;                 // block-uniform exit
  const int slot = blockIdx.x;
  const int e = slot ? (item.x & 7) : (item.x >> 3);
  const int tid = threadIdx.x;
  const int w = tid >> 6, l = tid & 63;
  const int wm = w >> 1, wn = w & 1;

  if (tid < 64)
    ids_lds[tid] = (tid < item.z) ? (int)ids[item.y + tid] : -1;
  __syncthreads();

  const int Lb = w * 1024 + l * 16;
  const _Float16* aptr[2];
  const _Float16* bptr[4];
  int ldstA[2], ldstB[4];
#pragma unroll
  for (int i = 0; i < 2; ++i) {
    const int L = i * 4096 + Lb;
    const int row = L >> 7;                       // 0..63
    const int cb = (L & 127) ^ ((row & 7) << 4);
    int t = ids_lds[row]; if (t < 0) t = 0;       // pad rows read token 0
    aptr[i] = xh + (size_t)t * DIM + (cb >> 1);
    ldstA[i] = i * 4096 + w * 1024;
  }
#pragma unroll
  for (int i = 0; i < 4; ++i) {
    const int L = i * 4096 + Lb;
    const int row = L >> 7;                       // 0..127
    const int cb = (L & 127) ^ ((row & 7) << 4);
    bptr[i] = WaT + (size_t)(e * 128 + row) * DIM + (cb >> 1);
    ldstB[i] = i * 4096 + w * 1024;
  }

  f32x4 acc[2][4];
#pragma unroll
  for (int p = 0; p < 2; ++p)
#pragma unroll
    for (int q = 0; q < 4; ++q)
#pragma unroll
      for (int j = 0; j < 4; ++j) acc[p][q][j] = 0.f;

  for (int kt = 0; kt < DIM; kt += 64) {
#pragma unroll
    for (int i = 0; i < 2; ++i)
      gload_lds16(aptr[i] + kt, ldsA + ldstA[i]);
#pragma unroll
    for (int i = 0; i < 4; ++i)
      gload_lds16(bptr[i] + kt, ldsB + ldstB[i]);
    __syncthreads();
#pragma unroll
    for (int kk = 0; kk < 2; ++kk) {
      const int kb = kk * 64 + ((l >> 4) << 4);
      f16x8 af[2], bfr[4];
#pragma unroll
      for (int mf = 0; mf < 2; ++mf) {
        const int r = (wm << 5) + (mf << 4) + (l & 15);
        af[mf] = *(const f16x8*)(ldsA + r * 128 + (kb ^ ((r & 7) << 4)));
      }
#pragma unroll
      for (int nf = 0; nf < 4; ++nf) {
        const int r = (wn << 6) + (nf << 4) + (l & 15);
        bfr[nf] = *(const f16x8*)(ldsB + r * 128 + (kb ^ ((r & 7) << 4)));
      }
#pragma unroll
      for (int mf = 0; mf < 2; ++mf)
#pragma unroll
        for (int nf = 0; nf < 4; ++nf)
          acc[mf][nf] = __builtin_amdgcn_mfma_f32_16x16x32_f16(
              af[mf], bfr[nf], acc[mf][nf], 0, 0, 0);
    }
    __syncthreads();
  }

  // epilogue: m = wm*32 + mf*16 + (l>>4)*4 + j; n = wn*64 + nf*16 + (l&15)
  const int cr = (l >> 4) << 2;
  const int cc = l & 15;
#pragma unroll
  for (int mf = 0; mf < 2; ++mf) {
    const int lr0 = (wm << 5) + (mf << 4) + cr;
#pragma unroll
    for (int j = 0; j < 4; ++j) {
      const int t = ids_lds[lr0 + j];
      if (t < 0) continue;
      const float cs = combine[(size_t)t * 8 + e];
      _Float16* yr = Yc + (size_t)t * 256 + slot * 128 + (wn << 6);
#pragma unroll
      for (int nf = 0; nf < 4; ++nf)
        yr[(nf << 4) + cc] = (_Float16)(acc[mf][nf][j] * cs);
    }
  }
}

// -------------------------------------------------------------- gemm2_pair
// out[t] = Yc[t][0:256] @ [Wb_a; Wb_b] for tokens in this tile's pair bin.
// T1 XCD swizzle: groups of 8 consecutive lids (same item -> same gathered
// A-tile) land on ONE XCD's L2 instead of 8, cutting cross-XCD A re-fetch.
__global__ __launch_bounds__(256) void gemm2_pair_kernel(
    const _Float16* __restrict__ Y, const _Float16* __restrict__ WbT,
    const unsigned short* __restrict__ ids, const int4* __restrict__ items,
    float* __restrict__ out)
{
  __shared__ __align__(16) char lds[32768];
  __shared__ int ids_lds[128];
  char* ldsA = lds;
  char* ldsB = lds + 16384;

  // XCD swizzle of the linear block id (nwg = 16*192 = 3072, %8 == 0)
  const int nbx = gridDim.x;                  // 16
  const int nwg = nbx * gridDim.y;
  int lid = blockIdx.y * nbx + blockIdx.x;
  lid = (lid & 7) * (nwg >> 3) + (lid >> 3);
  const int4 item = items[lid / nbx];
  if (item.x < 0) return;                 // block-uniform exit
  const int a = item.x >> 3, b = item.x & 7;
  const int n0 = (lid % nbx) * 128;
  const int tid = threadIdx.x;
  const int w = tid >> 6, l = tid & 63;
  const int wm = w >> 1, wn = w & 1;

  if (tid < 128)
    ids_lds[tid] = (tid < item.z) ? (int)ids[item.y + tid] : -1;
  __syncthreads();

  const int Lb = w * 1024 + l * 16;
  const _Float16* aptr[4];
  const _Float16* bptrA[4];
  const _Float16* bptrB[4];
  int ldst[4];
#pragma unroll
  for (int i = 0; i < 4; ++i) {
    const int L = i * 4096 + Lb;
    const int row = L >> 7;
    const int cb = (L & 127) ^ ((row & 7) << 4);
    int t = ids_lds[row]; if (t < 0) t = 0;       // pad rows read token 0
    aptr[i]  = Y + (size_t)t * 256 + (cb >> 1);
    bptrA[i] = WbT + (size_t)(n0 + row) * 1024 + a * 128 + (cb >> 1);
    bptrB[i] = WbT + (size_t)(n0 + row) * 1024 + b * 128 + (cb >> 1);
    ldst[i] = i * 4096 + w * 1024;
  }

  f32x4 acc[4][4];
#pragma unroll
  for (int p = 0; p < 4; ++p)
#pragma unroll
    for (int q = 0; q < 4; ++q)
#pragma unroll
      for (int j = 0; j < 4; ++j) acc[p][q][j] = 0.f;

#pragma unroll
  for (int kt = 0; kt < 4; ++kt) {
#pragma unroll
    for (int i = 0; i < 4; ++i) {
      gload_lds16(aptr[i] + kt * 64, ldsA + ldst[i]);
      const _Float16* bs = (kt < 2) ? (bptrA[i] + kt * 64)
                                    : (bptrB[i] + (kt - 2) * 64);
      gload_lds16(bs, ldsB + ldst[i]);
    }
    __syncthreads();
#pragma unroll
    for (int kk = 0; kk < 2; ++kk) {
      const int kb = kk * 64 + ((l >> 4) << 4);
      f16x8 af[4], bfr[4];
#pragma unroll
      for (int mf = 0; mf < 4; ++mf) {
        const int r = (wm << 6) + (mf << 4) + (l & 15);
        af[mf] = *(const f16x8*)(ldsA + r * 128 + (kb ^ ((r & 7) << 4)));
      }
#pragma unroll
      for (int nf = 0; nf < 4; ++nf) {
        const int r = (wn << 6) + (nf << 4) + (l & 15);
        bfr[nf] = *(const f16x8*)(ldsB + r * 128 + (kb ^ ((r & 7) << 4)));
      }
#pragma unroll
      for (int mf = 0; mf < 4; ++mf)
#pragma unroll
        for (int nf = 0; nf < 4; ++nf)
          acc[mf][nf] = __builtin_amdgcn_mfma_f32_16x16x32_f16(
              af[mf], bfr[nf], acc[mf][nf], 0, 0, 0);
    }
    __syncthreads();
  }

  // epilogue: scatter rows to out[token]
  const int cr = (l >> 4) << 2;
  const int cc = l & 15;
#pragma unroll
  for (int mf = 0; mf < 4; ++mf) {
    const int lr0 = (wm << 6) + (mf << 4) + cr;
#pragma unroll
    for (int j = 0; j < 4; ++j) {
      const int t = ids_lds[lr0 + j];
      if (t < 0) continue;
      float* orow = out + (size_t)t * NOUT + n0;
#pragma unroll
      for (int nf = 0; nf < 4; ++nf)
        orow[(wn << 6) + (nf << 4) + cc] = acc[mf][nf][j];
    }
  }
}

// ------------------------------------------------------------------ launch
extern "C" void kernel_launch(void* const* d_in, const int* in_sizes, int n_in,
                              void* d_out, int out_size, void* d_ws, size_t ws_size,
                              hipStream_t stream) {
  const float* x  = (const float*)d_in[0];   // [4,4096,2048]
  const float* rw = (const float*)d_in[1];   // [2048,8]
  const float* Wa = (const float*)d_in[2];   // [8,2048,128]
  const float* Wb = (const float*)d_in[3];   // [8,128,2048]
  float* out = (float*)d_out;                // [4,4096,2048]

  char* ws = (char*)d_ws;
  // workspace layout (total ~85.5 MB)
  _Float16* xh       = (_Float16*)(ws);                // 67,108,864 [T][2048]
  _Float16* WaT      = (_Float16*)(ws + 67108864);     //  4,194,304 [1024][2048]
  _Float16* WbT      = (_Float16*)(ws + 71303168);     //  4,194,304 [2048][1024]
  float*    combine  = (float*)   (ws + 75497472);     //    524,288 [T][8]
  int*      counts   = (int*)     (ws + 76021760);     //        256 [64]
  int4*     items64  = (int4*)    (ws + 76022016);     //      6,144 [384]
  int4*     items128 = (int4*)    (ws + 76028160);     //      3,072 [192]
  unsigned short* ids16 = (unsigned short*)(ws + 76031232); // 1,048,576 [64][CAP]
  _Float16* Yc       = (_Float16*)(ws + 77079808);     //  8,388,608 [T][256]
  float*    lgpart   = (float*)   (ws + 77079808);     // 2 MB [KSL][T][8], aliases Yc
  float*    ssqpart  = (float*)   (ws + 79177728);     // 256 KB [KSL][T], aliases Yc
  // (lgpart/ssqpart consumed by softmax before gemm1_pair writes Yc)

  // WaT[(e*128+r)][k] = Wa[e][k][r]
  transpose_cast_f16<<<dim3(4, 64, 8), dim3(32, 8), 0, stream>>>(
      Wa, WaT, 2048, 128, 2048, (long)128 * 2048);
  // WbT[n][e*128+r] = Wb[e][r][n]
  transpose_cast_f16<<<dim3(64, 4, 8), dim3(32, 8), 0, stream>>>(
      Wb, WbT, 128, 2048, 1024, 128);

  // also zeroes counts[] (block (0,0)) -- no separate memset node
  logits_fused_kernel<<<dim3(TOKENS / 128, KSL), 256, 0, stream>>>(
      x, rw, lgpart, ssqpart, xh, counts);

  softmax_top2_kernel<<<TOKENS / 256, 256, 0, stream>>>(
      lgpart, ssqpart, combine, counts, ids16);
  make_items_kernel<<<1, 64, 0, stream>>>(counts, items64, items128);

  // Yc[t][slot*128+r] = combine[t][e_slot] * (xh[t] . WaT[e_slot*128+r])
  gemm1_pair_kernel<<<dim3(2, 384), 256, 0, stream>>>(
      xh, WaT, combine, ids16, items64, Yc);
  // out[t] = Yc[t][0:256] @ [Wb_a; Wb_b]
  gemm2_pair_kernel<<<dim3(NOUT / 128, 192), 256, 0, stream>>>(
      Yc, WbT, ids16, items128, out);
}

// Round 18
// 181.235 us; speedup vs baseline: 1.0532x; 1.0252x over previous
//
#include <hip/hip_runtime.h>
#include <cstdint>
#include <cstddef>

#define TOKENS 16384
#define DIM    2048
#define NEXP   8
#define RANK   128
#define NOUT   2048
#define CAP    8192   // per-pair-bin token capacity (avg ~585, 14x headroom)
#define KSL    4      // logits K-slices (512 wide each) -- R11-proven config

typedef __attribute__((ext_vector_type(4))) float    f32x4;
typedef __attribute__((ext_vector_type(8))) _Float16 f16x8;
typedef __attribute__((ext_vector_type(4))) _Float16 f16x4;

// ---------------------------------------------------------------- utilities
__device__ __forceinline__ void gload_lds16(const void* g, void* l) {
  __builtin_amdgcn_global_load_lds(
      (const __attribute__((address_space(1))) void*)g,
      (__attribute__((address_space(3))) void*)l, 16, 0, 0);
}

// ------------------------------------------------- transpose + cast to f16
// in: [E][R][C] fp32.  out element: out[e*obase + c*ostride + r] = in[e][r][c]
__global__ __launch_bounds__(256) void transpose_cast_f16(
    const float* __restrict__ in, _Float16* __restrict__ out,
    int R, int C, long ostride, long obase)
{
  __shared__ float tile[32][33];
  const int e = blockIdx.z;
  const float* ine = in + (size_t)e * R * C;
  const int c0 = blockIdx.x * 32, r0 = blockIdx.y * 32;
  const int tx = threadIdx.x, ty = threadIdx.y;
#pragma unroll
  for (int j = 0; j < 32; j += 8)
    tile[ty + j][tx] = ine[(size_t)(r0 + ty + j) * C + (c0 + tx)];
  __syncthreads();
#pragma unroll
  for (int j = 0; j < 32; j += 8)
    out[(size_t)e * obase + (size_t)(c0 + ty + j) * ostride + (r0 + tx)] =
        (_Float16)tile[tx][ty + j];
}

// ------------------------------------------------------------ logits_fused
// R11-proven: 64KB LDS, 512-wide K slices, A staged via gload_lds into
// XOR-swizzled [128][256B] fp32 tile; rw split-cast (double-f16) in LDS.
// Also zeroes counts[64] from block (0,0).
__global__ __launch_bounds__(256) void logits_fused_kernel(
    const float* __restrict__ x, const float* __restrict__ rw,
    float* __restrict__ lgpart, float* __restrict__ ssqpart,
    _Float16* __restrict__ xh, int* __restrict__ counts)
{
  __shared__ __align__(16) char lds[65536];
  char* ldsA  = lds;           // [128 rows][256B fp32], swizzled
  char* ldsBh = lds + 32768;   // [16][1024B f16] hi (rows 8..15 zero)
  char* ldsBe = lds + 49152;   // [16][1024B f16] lo
  const int tid = threadIdx.x;
  const int w = tid >> 6, l = tid & 63;
  const int m0 = blockIdx.x * 128;
  const int ks = blockIdx.y;            // K-slice, 512 wide
  const int kbase = ks * 512;

  if (blockIdx.x == 0 && ks == 0 && tid < 64) counts[tid] = 0;

  // split-cast rw slice -> (ldsBh, ldsBe), byte ^= ((n&7)<<4); rows 8..15 = 0
#pragma unroll
  for (int i = 0; i < 32; ++i) {
    const int idx = tid * 32 + i;       // 0..8191 over [16][512]
    const int n = idx >> 9, k = idx & 511;
    const float v = (n < 8) ? rw[(size_t)(kbase + k) * 8 + n] : 0.f;
    const _Float16 h = (_Float16)v;
    const _Float16 e = (_Float16)(v - (float)h);
    const int off = n * 1024 + ((k * 2) ^ ((n & 7) << 4));
    *(_Float16*)(ldsBh + off) = h;
    *(_Float16*)(ldsBe + off) = e;
  }

  const int Lb = w * 1024 + l * 16;
  const float* agp[8];
  int ldst[8];
#pragma unroll
  for (int i = 0; i < 8; ++i) {
    const int L = i * 4096 + Lb;
    const int row = L >> 8;                       // 256B fp32 rows
    const int cb = (L & 255) ^ ((row & 7) << 4);
    agp[i] = x + (size_t)(m0 + row) * DIM + kbase + (cb >> 2);
    ldst[i] = i * 4096 + w * 1024;
  }

  f32x4 acc[2];
  float ssl[2] = {0.f, 0.f};
#pragma unroll
  for (int mf = 0; mf < 2; ++mf)
#pragma unroll
    for (int j = 0; j < 4; ++j) acc[mf][j] = 0.f;

  for (int st = 0; st < 8; ++st) {
#pragma unroll
    for (int i = 0; i < 8; ++i)
      gload_lds16(agp[i] + st * 64, ldsA + ldst[i]);
    __syncthreads();                     // covers B writes on st==0 too
#pragma unroll
    for (int kk = 0; kk < 2; ++kk) {
      const int n = l & 15;
      const int bko = n * 1024 +
          ((st * 128 + kk * 64 + ((l >> 4) << 4)) ^ ((n & 7) << 4));
      const f16x8 bh = *(const f16x8*)(ldsBh + bko);
      const f16x8 be = *(const f16x8*)(ldsBe + bko);
#pragma unroll
      for (int mf = 0; mf < 2; ++mf) {
        const int r = w * 32 + mf * 16 + (l & 15);
        const int s = (r & 7) << 4;
        const int c0 = kk * 128 + ((l >> 4) << 5);
        const f32x4 va = *(const f32x4*)(ldsA + r * 256 + ((c0) ^ s));
        const f32x4 vb = *(const f32x4*)(ldsA + r * 256 + ((c0 + 16) ^ s));
        float f[8] = {va[0], va[1], va[2], va[3], vb[0], vb[1], vb[2], vb[3]};
        f16x8 ah, ae;
#pragma unroll
        for (int j = 0; j < 8; ++j) {
          ah[j] = (_Float16)f[j];
          ae[j] = (_Float16)(f[j] - (float)ah[j]);
          ssl[mf] = fmaf(f[j], f[j], ssl[mf]);
        }
        // xh = f16(x): fragment covers 8 contiguous cols of row m0+r
        *(f16x8*)(xh + (size_t)(m0 + r) * DIM + kbase + st * 64 + kk * 32 +
                  ((l >> 4) << 3)) = ah;
        acc[mf] = __builtin_amdgcn_mfma_f32_16x16x32_f16(ae, bh, acc[mf], 0, 0, 0);
        acc[mf] = __builtin_amdgcn_mfma_f32_16x16x32_f16(ah, be, acc[mf], 0, 0, 0);
        acc[mf] = __builtin_amdgcn_mfma_f32_16x16x32_f16(ah, bh, acc[mf], 0, 0, 0);
      }
    }
    __syncthreads();
  }

  // lgpart: C/D layout col = lane&15, row = (lane>>4)*4 + j
  const int col = l & 15;
  if (col < 8) {
#pragma unroll
    for (int mf = 0; mf < 2; ++mf) {
      const int rbase = m0 + w * 32 + mf * 16 + ((l >> 4) << 2);
#pragma unroll
      for (int j = 0; j < 4; ++j)
        lgpart[((size_t)ks * TOKENS + rbase + j) * 8 + col] = acc[mf][j];
    }
  }
  // ssqpart: lane's ssl[mf] covers 128 cols of row w*32+mf*16+(l&15)
#pragma unroll
  for (int mf = 0; mf < 2; ++mf) {
    float s = ssl[mf];
    s += __shfl_xor(s, 16, 64);
    s += __shfl_xor(s, 32, 64);
    if (l < 16)
      ssqpart[(size_t)ks * TOKENS + m0 + w * 32 + mf * 16 + l] = s;
  }
}

// ------------------------------------------------------------ softmax_top2
// combine[t][e]; bins token t into pair bin a*8+b (a<b). Bin order is
// nondeterministic (atomicAdd) but each token's output value is
// order-independent -> deterministic result.
__global__ __launch_bounds__(256) void softmax_top2_kernel(
    const float* __restrict__ lgpart, const float* __restrict__ ssqpart,
    float* __restrict__ combine, int* __restrict__ counts,
    unsigned short* __restrict__ ids16)
{
  const size_t t = (size_t)blockIdx.x * 256 + threadIdx.x;
  float ss = 0.f;
  float lg[8];
#pragma unroll
  for (int e = 0; e < 8; ++e) lg[e] = 0.f;
#pragma unroll
  for (int ks = 0; ks < KSL; ++ks) {
    ss += ssqpart[(size_t)ks * TOKENS + t];
    const float* p = lgpart + ((size_t)ks * TOKENS + t) * 8;
    float4 a = *(const float4*)(p);
    float4 b = *(const float4*)(p + 4);
    lg[0] += a.x; lg[1] += a.y; lg[2] += a.z; lg[3] += a.w;
    lg[4] += b.x; lg[5] += b.y; lg[6] += b.z; lg[7] += b.w;
  }
  const float iv = 1.f / fmaxf(sqrtf(ss), 1e-12f);
#pragma unroll
  for (int e = 0; e < 8; ++e) lg[e] *= iv;
  float b1 = lg[0]; int e1 = 0;
#pragma unroll
  for (int e = 1; e < 8; ++e)
    if (lg[e] > b1) { b1 = lg[e]; e1 = e; }
  float b2 = -3.4e38f; int e2 = 0;
#pragma unroll
  for (int e = 0; e < 8; ++e)
    if (e != e1 && lg[e] > b2) { b2 = lg[e]; e2 = e; }
  const float p2 = expf(b2 - b1);
  const float w1 = 1.f / (1.f + p2);
  const float w2 = p2 * w1;
  float ov[8];
#pragma unroll
  for (int e = 0; e < 8; ++e)
    ov[e] = (e == e1) ? w1 : ((e == e2) ? w2 : 0.f);
  float4* cp = (float4*)(combine + t * 8);
  cp[0] = make_float4(ov[0], ov[1], ov[2], ov[3]);
  cp[1] = make_float4(ov[4], ov[5], ov[6], ov[7]);

  const int a = min(e1, e2), b = max(e1, e2);
  const int bin = a * 8 + b;
  const int pos = atomicAdd(&counts[bin], 1);
  if (pos < CAP) ids16[bin * CAP + pos] = (unsigned short)t;
}

// -------------------------------------------------------------- make_items
// Wave-parallel builder of two work lists: 64-row tiles for gemm1 (<=320,
// padded to 384) and 128-row tiles for gemm2 (<=192). Lane b owns bin b.
__global__ void make_items_kernel(const int* __restrict__ counts,
                                  int4* __restrict__ items64,
                                  int4* __restrict__ items128)
{
  const int l = threadIdx.x;            // 64 lanes, one per bin
  const int c = min(counts[l], CAP);
  const int n64 = (c + 63) >> 6;
  const int n128 = (c + 127) >> 7;
  int p64 = n64, p128 = n128;           // inclusive prefix sums
#pragma unroll
  for (int m = 1; m < 64; m <<= 1) {
    int u = __shfl_up(p64, m, 64);  if (l >= m) p64 += u;
    int v = __shfl_up(p128, m, 64); if (l >= m) p128 += v;
  }
  const int tot64 = __shfl(p64, 63, 64);
  const int tot128 = __shfl(p128, 63, 64);
  int j = p64 - n64;
  for (int s = 0; s < c; s += 64, ++j)
    items64[j] = make_int4(l, l * CAP + s, min(64, c - s), 0);
  j = p128 - n128;
  for (int s = 0; s < c; s += 128, ++j)
    items128[j] = make_int4(l, l * CAP + s, min(128, c - s), 0);
  for (int k = tot64 + l; k < 384; k += 64) items64[k] = make_int4(-1, 0, 0, 0);
  for (int k = tot128 + l; k < 192; k += 64) items128[k] = make_int4(-1, 0, 0, 0);
}

// -------------------------------------------------------------- gemm1_pair
// Grouped by pair bin, BM=64 tiles (768-block grid ~3/CU, halved tail):
// Yc[t][slot*128+r] = combine[t][e_slot] * (xh[t] . WaT[e*128+r]).
// K=2048 (32 BK=64 steps), A rows gathered by token id. 24.5KB LDS.
__global__ __launch_bounds__(256) void gemm1_pair_kernel(
    const _Float16* __restrict__ xh, const _Float16* __restrict__ WaT,
    const float* __restrict__ combine, const unsigned short* __restrict__ ids,
    const int4* __restrict__ items, _Float16* __restrict__ Yc)
{
  __shared__ __align__(16) char lds[24576];
  __shared__ int ids_lds[64];
  char* ldsA = lds;              // [64 rows][128B]
  char* ldsB = lds + 8192;       // [128 rows][128B]
  const int4 item = items[blockIdx.y];
  if (item.x < 0) return;                 // block-uniform exit
  const int slot = blockIdx.x;
  const int e = slot ? (item.x & 7) : (item.x >> 3);
  const int tid = threadIdx.x;
  const int w = tid >> 6, l = tid & 63;
  const int wm = w >> 1, wn = w & 1;

  if (tid < 64)
    ids_lds[tid] = (tid < item.z) ? (int)ids[item.y + tid] : -1;
  __syncthreads();

  const int Lb = w * 1024 + l * 16;
  const _Float16* aptr[2];
  const _Float16* bptr[4];
  int ldstA[2], ldstB[4];
#pragma unroll
  for (int i = 0; i < 2; ++i) {
    const int L = i * 4096 + Lb;
    const int row = L >> 7;                       // 0..63
    const int cb = (L & 127) ^ ((row & 7) << 4);
    int t = ids_lds[row]; if (t < 0) t = 0;       // pad rows read token 0
    aptr[i] = xh + (size_t)t * DIM + (cb >> 1);
    ldstA[i] = i * 4096 + w * 1024;
  }
#pragma unroll
  for (int i = 0; i < 4; ++i) {
    const int L = i * 4096 + Lb;
    const int row = L >> 7;                       // 0..127
    const int cb = (L & 127) ^ ((row & 7) << 4);
    bptr[i] = WaT + (size_t)(e * 128 + row) * DIM + (cb >> 1);
    ldstB[i] = i * 4096 + w * 1024;
  }

  f32x4 acc[2][4];
#pragma unroll
  for (int p = 0; p < 2; ++p)
#pragma unroll
    for (int q = 0; q < 4; ++q)
#pragma unroll
      for (int j = 0; j < 4; ++j) acc[p][q][j] = 0.f;

  for (int kt = 0; kt < DIM; kt += 64) {
#pragma unroll
    for (int i = 0; i < 2; ++i)
      gload_lds16(aptr[i] + kt, ldsA + ldstA[i]);
#pragma unroll
    for (int i = 0; i < 4; ++i)
      gload_lds16(bptr[i] + kt, ldsB + ldstB[i]);
    __syncthreads();
#pragma unroll
    for (int kk = 0; kk < 2; ++kk) {
      const int kb = kk * 64 + ((l >> 4) << 4);
      f16x8 af[2], bfr[4];
#pragma unroll
      for (int mf = 0; mf < 2; ++mf) {
        const int r = (wm << 5) + (mf << 4) + (l & 15);
        af[mf] = *(const f16x8*)(ldsA + r * 128 + (kb ^ ((r & 7) << 4)));
      }
#pragma unroll
      for (int nf = 0; nf < 4; ++nf) {
        const int r = (wn << 6) + (nf << 4) + (l & 15);
        bfr[nf] = *(const f16x8*)(ldsB + r * 128 + (kb ^ ((r & 7) << 4)));
      }
#pragma unroll
      for (int mf = 0; mf < 2; ++mf)
#pragma unroll
        for (int nf = 0; nf < 4; ++nf)
          acc[mf][nf] = __builtin_amdgcn_mfma_f32_16x16x32_f16(
              af[mf], bfr[nf], acc[mf][nf], 0, 0, 0);
    }
    __syncthreads();
  }

  // epilogue: m = wm*32 + mf*16 + (l>>4)*4 + j; n = wn*64 + nf*16 + (l&15)
  const int cr = (l >> 4) << 2;
  const int cc = l & 15;
#pragma unroll
  for (int mf = 0; mf < 2; ++mf) {
    const int lr0 = (wm << 5) + (mf << 4) + cr;
#pragma unroll
    for (int j = 0; j < 4; ++j) {
      const int t = ids_lds[lr0 + j];
      if (t < 0) continue;
      const float cs = combine[(size_t)t * 8 + e];
      _Float16* yr = Yc + (size_t)t * 256 + slot * 128 + (wn << 6);
#pragma unroll
      for (int nf = 0; nf < 4; ++nf)
        yr[(nf << 4) + cc] = (_Float16)(acc[mf][nf][j] * cs);
    }
  }
}

// -------------------------------------------------------------- gemm2_pair
// out[t] = Yc[t][0:256] @ [Wb_a; Wb_b] for tokens in this tile's pair bin.
__global__ __launch_bounds__(256) void gemm2_pair_kernel(
    const _Float16* __restrict__ Y, const _Float16* __restrict__ WbT,
    const unsigned short* __restrict__ ids, const int4* __restrict__ items,
    float* __restrict__ out)
{
  __shared__ __align__(16) char lds[32768];
  __shared__ int ids_lds[128];
  char* ldsA = lds;
  char* ldsB = lds + 16384;
  const int4 item = items[blockIdx.y];
  if (item.x < 0) return;                 // block-uniform exit
  const int a = item.x >> 3, b = item.x & 7;
  const int n0 = blockIdx.x * 128;
  const int tid = threadIdx.x;
  const int w = tid >> 6, l = tid & 63;
  const int wm = w >> 1, wn = w & 1;

  if (tid < 128)
    ids_lds[tid] = (tid < item.z) ? (int)ids[item.y + tid] : -1;
  __syncthreads();

  const int Lb = w * 1024 + l * 16;
  const _Float16* aptr[4];
  const _Float16* bptrA[4];
  const _Float16* bptrB[4];
  int ldst[4];
#pragma unroll
  for (int i = 0; i < 4; ++i) {
    const int L = i * 4096 + Lb;
    const int row = L >> 7;
    const int cb = (L & 127) ^ ((row & 7) << 4);
    int t = ids_lds[row]; if (t < 0) t = 0;       // pad rows read token 0
    aptr[i]  = Y + (size_t)t * 256 + (cb >> 1);
    bptrA[i] = WbT + (size_t)(n0 + row) * 1024 + a * 128 + (cb >> 1);
    bptrB[i] = WbT + (size_t)(n0 + row) * 1024 + b * 128 + (cb >> 1);
    ldst[i] = i * 4096 + w * 1024;
  }

  f32x4 acc[4][4];
#pragma unroll
  for (int p = 0; p < 4; ++p)
#pragma unroll
    for (int q = 0; q < 4; ++q)
#pragma unroll
      for (int j = 0; j < 4; ++j) acc[p][q][j] = 0.f;

#pragma unroll
  for (int kt = 0; kt < 4; ++kt) {
#pragma unroll
    for (int i = 0; i < 4; ++i) {
      gload_lds16(aptr[i] + kt * 64, ldsA + ldst[i]);
      const _Float16* bs = (kt < 2) ? (bptrA[i] + kt * 64)
                                    : (bptrB[i] + (kt - 2) * 64);
      gload_lds16(bs, ldsB + ldst[i]);
    }
    __syncthreads();
#pragma unroll
    for (int kk = 0; kk < 2; ++kk) {
      const int kb = kk * 64 + ((l >> 4) << 4);
      f16x8 af[4], bfr[4];
#pragma unroll
      for (int mf = 0; mf < 4; ++mf) {
        const int r = (wm << 6) + (mf << 4) + (l & 15);
        af[mf] = *(const f16x8*)(ldsA + r * 128 + (kb ^ ((r & 7) << 4)));
      }
#pragma unroll
      for (int nf = 0; nf < 4; ++nf) {
        const int r = (wn << 6) + (nf << 4) + (l & 15);
        bfr[nf] = *(const f16x8*)(ldsB + r * 128 + (kb ^ ((r & 7) << 4)));
      }
#pragma unroll
      for (int mf = 0; mf < 4; ++mf)
#pragma unroll
        for (int nf = 0; nf < 4; ++nf)
          acc[mf][nf] = __builtin_amdgcn_mfma_f32_16x16x32_f16(
              af[mf], bfr[nf], acc[mf][nf], 0, 0, 0);
    }
    __syncthreads();
  }

  // epilogue: scatter rows to out[token]
  const int cr = (l >> 4) << 2;
  const int cc = l & 15;
#pragma unroll
  for (int mf = 0; mf < 4; ++mf) {
    const int lr0 = (wm << 6) + (mf << 4) + cr;
#pragma unroll
    for (int j = 0; j < 4; ++j) {
      const int t = ids_lds[lr0 + j];
      if (t < 0) continue;
      float* orow = out + (size_t)t * NOUT + n0;
#pragma unroll
      for (int nf = 0; nf < 4; ++nf)
        orow[(wn << 6) + (nf << 4) + cc] = acc[mf][nf][j];
    }
  }
}

// ------------------------------------------------------------------ launch
extern "C" void kernel_launch(void* const* d_in, const int* in_sizes, int n_in,
                              void* d_out, int out_size, void* d_ws, size_t ws_size,
                              hipStream_t stream) {
  const float* x  = (const float*)d_in[0];   // [4,4096,2048]
  const float* rw = (const float*)d_in[1];   // [2048,8]
  const float* Wa = (const float*)d_in[2];   // [8,2048,128]
  const float* Wb = (const float*)d_in[3];   // [8,128,2048]
  float* out = (float*)d_out;                // [4,4096,2048]

  char* ws = (char*)d_ws;
  // workspace layout (total ~85.5 MB)
  _Float16* xh       = (_Float16*)(ws);                // 67,108,864 [T][2048]
  _Float16* WaT      = (_Float16*)(ws + 67108864);     //  4,194,304 [1024][2048]
  _Float16* WbT      = (_Float16*)(ws + 71303168);     //  4,194,304 [2048][1024]
  float*    combine  = (float*)   (ws + 75497472);     //    524,288 [T][8]
  int*      counts   = (int*)     (ws + 76021760);     //        256 [64]
  int4*     items64  = (int4*)    (ws + 76022016);     //      6,144 [384]
  int4*     items128 = (int4*)    (ws + 76028160);     //      3,072 [192]
  unsigned short* ids16 = (unsigned short*)(ws + 76031232); // 1,048,576 [64][CAP]
  _Float16* Yc       = (_Float16*)(ws + 77079808);     //  8,388,608 [T][256]
  float*    lgpart   = (float*)   (ws + 77079808);     // 2 MB [KSL][T][8], aliases Yc
  float*    ssqpart  = (float*)   (ws + 79177728);     // 256 KB [KSL][T], aliases Yc
  // (lgpart/ssqpart consumed by softmax before gemm1_pair writes Yc)

  // WaT[(e*128+r)][k] = Wa[e][k][r]
  transpose_cast_f16<<<dim3(4, 64, 8), dim3(32, 8), 0, stream>>>(
      Wa, WaT, 2048, 128, 2048, (long)128 * 2048);
  // WbT[n][e*128+r] = Wb[e][r][n]
  transpose_cast_f16<<<dim3(64, 4, 8), dim3(32, 8), 0, stream>>>(
      Wb, WbT, 128, 2048, 1024, 128);

  // also zeroes counts[] (block (0,0)) -- no separate memset node
  logits_fused_kernel<<<dim3(TOKENS / 128, KSL), 256, 0, stream>>>(
      x, rw, lgpart, ssqpart, xh, counts);

  softmax_top2_kernel<<<TOKENS / 256, 256, 0, stream>>>(
      lgpart, ssqpart, combine, counts, ids16);
  make_items_kernel<<<1, 64, 0, stream>>>(counts, items64, items128);

  // Yc[t][slot*128+r] = combine[t][e_slot] * (xh[t] . WaT[e_slot*128+r])
  gemm1_pair_kernel<<<dim3(2, 384), 256, 0, stream>>>(
      xh, WaT, combine, ids16, items64, Yc);
  // out[t] = Yc[t][0:256] @ [Wb_a; Wb_b]
  gemm2_pair_kernel<<<dim3(NOUT / 128, 192), 256, 0, stream>>>(
      Yc, WbT, ids16, items128, out);
}

// Round 19
// 180.923 us; speedup vs baseline: 1.0550x; 1.0017x over previous
//
#include <hip/hip_runtime.h>
#include <cstdint>
#include <cstddef>

#define TOKENS 16384
#define DIM    2048
#define NEXP   8
#define RANK   128
#define NOUT   2048
#define CAP    8192   // per-pair-bin token capacity (avg ~585, 14x headroom)
#define KSL    4      // logits K-slices (512 wide each) -- R11-proven config

typedef __attribute__((ext_vector_type(4))) float    f32x4;
typedef __attribute__((ext_vector_type(8))) _Float16 f16x8;
typedef __attribute__((ext_vector_type(4))) _Float16 f16x4;

// ---------------------------------------------------------------- utilities
__device__ __forceinline__ void gload_lds16(const void* g, void* l) {
  __builtin_amdgcn_global_load_lds(
      (const __attribute__((address_space(1))) void*)g,
      (__attribute__((address_space(3))) void*)l, 16, 0, 0);
}

// ------------------------------------------------- transpose + cast to f16
// in: [E][R][C] fp32.  out element: out[e*obase + c*ostride + r] = in[e][r][c]
__global__ __launch_bounds__(256) void transpose_cast_f16(
    const float* __restrict__ in, _Float16* __restrict__ out,
    int R, int C, long ostride, long obase)
{
  __shared__ float tile[32][33];
  const int e = blockIdx.z;
  const float* ine = in + (size_t)e * R * C;
  const int c0 = blockIdx.x * 32, r0 = blockIdx.y * 32;
  const int tx = threadIdx.x, ty = threadIdx.y;
#pragma unroll
  for (int j = 0; j < 32; j += 8)
    tile[ty + j][tx] = ine[(size_t)(r0 + ty + j) * C + (c0 + tx)];
  __syncthreads();
#pragma unroll
  for (int j = 0; j < 32; j += 8)
    out[(size_t)e * obase + (size_t)(c0 + ty + j) * ostride + (r0 + tx)] =
        (_Float16)tile[tx][ty + j];
}

// ------------------------------------------------------------ logits_fused
// R11-proven: 64KB LDS, 512-wide K slices, A staged via gload_lds into
// XOR-swizzled [128][256B] fp32 tile; rw split-cast (double-f16) in LDS.
// Also zeroes counts[64] from block (0,0).
__global__ __launch_bounds__(256) void logits_fused_kernel(
    const float* __restrict__ x, const float* __restrict__ rw,
    float* __restrict__ lgpart, float* __restrict__ ssqpart,
    _Float16* __restrict__ xh, int* __restrict__ counts)
{
  __shared__ __align__(16) char lds[65536];
  char* ldsA  = lds;           // [128 rows][256B fp32], swizzled
  char* ldsBh = lds + 32768;   // [16][1024B f16] hi (rows 8..15 zero)
  char* ldsBe = lds + 49152;   // [16][1024B f16] lo
  const int tid = threadIdx.x;
  const int w = tid >> 6, l = tid & 63;
  const int m0 = blockIdx.x * 128;
  const int ks = blockIdx.y;            // K-slice, 512 wide
  const int kbase = ks * 512;

  if (blockIdx.x == 0 && ks == 0 && tid < 64) counts[tid] = 0;

  // split-cast rw slice -> (ldsBh, ldsBe), byte ^= ((n&7)<<4); rows 8..15 = 0
#pragma unroll
  for (int i = 0; i < 32; ++i) {
    const int idx = tid * 32 + i;       // 0..8191 over [16][512]
    const int n = idx >> 9, k = idx & 511;
    const float v = (n < 8) ? rw[(size_t)(kbase + k) * 8 + n] : 0.f;
    const _Float16 h = (_Float16)v;
    const _Float16 e = (_Float16)(v - (float)h);
    const int off = n * 1024 + ((k * 2) ^ ((n & 7) << 4));
    *(_Float16*)(ldsBh + off) = h;
    *(_Float16*)(ldsBe + off) = e;
  }

  const int Lb = w * 1024 + l * 16;
  const float* agp[8];
  int ldst[8];
#pragma unroll
  for (int i = 0; i < 8; ++i) {
    const int L = i * 4096 + Lb;
    const int row = L >> 8;                       // 256B fp32 rows
    const int cb = (L & 255) ^ ((row & 7) << 4);
    agp[i] = x + (size_t)(m0 + row) * DIM + kbase + (cb >> 2);
    ldst[i] = i * 4096 + w * 1024;
  }

  f32x4 acc[2];
  float ssl[2] = {0.f, 0.f};
#pragma unroll
  for (int mf = 0; mf < 2; ++mf)
#pragma unroll
    for (int j = 0; j < 4; ++j) acc[mf][j] = 0.f;

  for (int st = 0; st < 8; ++st) {
#pragma unroll
    for (int i = 0; i < 8; ++i)
      gload_lds16(agp[i] + st * 64, ldsA + ldst[i]);
    __syncthreads();                     // covers B writes on st==0 too
#pragma unroll
    for (int kk = 0; kk < 2; ++kk) {
      const int n = l & 15;
      const int bko = n * 1024 +
          ((st * 128 + kk * 64 + ((l >> 4) << 4)) ^ ((n & 7) << 4));
      const f16x8 bh = *(const f16x8*)(ldsBh + bko);
      const f16x8 be = *(const f16x8*)(ldsBe + bko);
#pragma unroll
      for (int mf = 0; mf < 2; ++mf) {
        const int r = w * 32 + mf * 16 + (l & 15);
        const int s = (r & 7) << 4;
        const int c0 = kk * 128 + ((l >> 4) << 5);
        const f32x4 va = *(const f32x4*)(ldsA + r * 256 + ((c0) ^ s));
        const f32x4 vb = *(const f32x4*)(ldsA + r * 256 + ((c0 + 16) ^ s));
        float f[8] = {va[0], va[1], va[2], va[3], vb[0], vb[1], vb[2], vb[3]};
        f16x8 ah, ae;
#pragma unroll
        for (int j = 0; j < 8; ++j) {
          ah[j] = (_Float16)f[j];
          ae[j] = (_Float16)(f[j] - (float)ah[j]);
          ssl[mf] = fmaf(f[j], f[j], ssl[mf]);
        }
        // xh = f16(x): fragment covers 8 contiguous cols of row m0+r
        *(f16x8*)(xh + (size_t)(m0 + r) * DIM + kbase + st * 64 + kk * 32 +
                  ((l >> 4) << 3)) = ah;
        acc[mf] = __builtin_amdgcn_mfma_f32_16x16x32_f16(ae, bh, acc[mf], 0, 0, 0);
        acc[mf] = __builtin_amdgcn_mfma_f32_16x16x32_f16(ah, be, acc[mf], 0, 0, 0);
        acc[mf] = __builtin_amdgcn_mfma_f32_16x16x32_f16(ah, bh, acc[mf], 0, 0, 0);
      }
    }
    __syncthreads();
  }

  // lgpart: C/D layout col = lane&15, row = (lane>>4)*4 + j
  const int col = l & 15;
  if (col < 8) {
#pragma unroll
    for (int mf = 0; mf < 2; ++mf) {
      const int rbase = m0 + w * 32 + mf * 16 + ((l >> 4) << 2);
#pragma unroll
      for (int j = 0; j < 4; ++j)
        lgpart[((size_t)ks * TOKENS + rbase + j) * 8 + col] = acc[mf][j];
    }
  }
  // ssqpart: lane's ssl[mf] covers 128 cols of row w*32+mf*16+(l&15)
#pragma unroll
  for (int mf = 0; mf < 2; ++mf) {
    float s = ssl[mf];
    s += __shfl_xor(s, 16, 64);
    s += __shfl_xor(s, 32, 64);
    if (l < 16)
      ssqpart[(size_t)ks * TOKENS + m0 + w * 32 + mf * 16 + l] = s;
  }
}

// ------------------------------------------------------------ softmax_top2
// combine[t][e]; bins token t into pair bin a*8+b (a<b). Bin order is
// nondeterministic (atomicAdd) but each token's output value is
// order-independent -> deterministic result.
__global__ __launch_bounds__(256) void softmax_top2_kernel(
    const float* __restrict__ lgpart, const float* __restrict__ ssqpart,
    float* __restrict__ combine, int* __restrict__ counts,
    unsigned short* __restrict__ ids16)
{
  const size_t t = (size_t)blockIdx.x * 256 + threadIdx.x;
  float ss = 0.f;
  float lg[8];
#pragma unroll
  for (int e = 0; e < 8; ++e) lg[e] = 0.f;
#pragma unroll
  for (int ks = 0; ks < KSL; ++ks) {
    ss += ssqpart[(size_t)ks * TOKENS + t];
    const float* p = lgpart + ((size_t)ks * TOKENS + t) * 8;
    float4 a = *(const float4*)(p);
    float4 b = *(const float4*)(p + 4);
    lg[0] += a.x; lg[1] += a.y; lg[2] += a.z; lg[3] += a.w;
    lg[4] += b.x; lg[5] += b.y; lg[6] += b.z; lg[7] += b.w;
  }
  const float iv = 1.f / fmaxf(sqrtf(ss), 1e-12f);
#pragma unroll
  for (int e = 0; e < 8; ++e) lg[e] *= iv;
  float b1 = lg[0]; int e1 = 0;
#pragma unroll
  for (int e = 1; e < 8; ++e)
    if (lg[e] > b1) { b1 = lg[e]; e1 = e; }
  float b2 = -3.4e38f; int e2 = 0;
#pragma unroll
  for (int e = 0; e < 8; ++e)
    if (e != e1 && lg[e] > b2) { b2 = lg[e]; e2 = e; }
  const float p2 = expf(b2 - b1);
  const float w1 = 1.f / (1.f + p2);
  const float w2 = p2 * w1;
  float ov[8];
#pragma unroll
  for (int e = 0; e < 8; ++e)
    ov[e] = (e == e1) ? w1 : ((e == e2) ? w2 : 0.f);
  float4* cp = (float4*)(combine + t * 8);
  cp[0] = make_float4(ov[0], ov[1], ov[2], ov[3]);
  cp[1] = make_float4(ov[4], ov[5], ov[6], ov[7]);

  const int a = min(e1, e2), b = max(e1, e2);
  const int bin = a * 8 + b;
  const int pos = atomicAdd(&counts[bin], 1);
  if (pos < CAP) ids16[bin * CAP + pos] = (unsigned short)t;
}

// -------------------------------------------------------------- make_items
// Wave-parallel builder of two work lists: 64-row tiles for gemm1 (<=320,
// padded to 384) and 128-row tiles for gemm2 (<=192). Lane b owns bin b.
__global__ void make_items_kernel(const int* __restrict__ counts,
                                  int4* __restrict__ items64,
                                  int4* __restrict__ items128)
{
  const int l = threadIdx.x;            // 64 lanes, one per bin
  const int c = min(counts[l], CAP);
  const int n64 = (c + 63) >> 6;
  const int n128 = (c + 127) >> 7;
  int p64 = n64, p128 = n128;           // inclusive prefix sums
#pragma unroll
  for (int m = 1; m < 64; m <<= 1) {
    int u = __shfl_up(p64, m, 64);  if (l >= m) p64 += u;
    int v = __shfl_up(p128, m, 64); if (l >= m) p128 += v;
  }
  const int tot64 = __shfl(p64, 63, 64);
  const int tot128 = __shfl(p128, 63, 64);
  int j = p64 - n64;
  for (int s = 0; s < c; s += 64, ++j)
    items64[j] = make_int4(l, l * CAP + s, min(64, c - s), 0);
  j = p128 - n128;
  for (int s = 0; s < c; s += 128, ++j)
    items128[j] = make_int4(l, l * CAP + s, min(128, c - s), 0);
  for (int k = tot64 + l; k < 384; k += 64) items64[k] = make_int4(-1, 0, 0, 0);
  for (int k = tot128 + l; k < 192; k += 64) items128[k] = make_int4(-1, 0, 0, 0);
}

// -------------------------------------------------------------- gemm1_pair
// Grouped by pair bin, BM=64 tiles (768-block grid ~3/CU, halved tail):
// Yc[t][slot*128+r] = combine[t][e_slot] * (xh[t] . WaT[e*128+r]).
// K=2048 (32 BK=64 steps), A rows gathered by token id. 24.5KB LDS.
__global__ __launch_bounds__(256) void gemm1_pair_kernel(
    const _Float16* __restrict__ xh, const _Float16* __restrict__ WaT,
    const float* __restrict__ combine, const unsigned short* __restrict__ ids,
    const int4* __restrict__ items, _Float16* __restrict__ Yc)
{
  __shared__ __align__(16) char lds[24576];
  __shared__ int ids_lds[64];
  char* ldsA = lds;              // [64 rows][128B]
  char* ldsB = lds + 8192;       // [128 rows][128B]
  const int4 item = items[blockIdx.y];
  if (item.x < 0) return;                 // block-uniform exit
  const int slot = blockIdx.x;
  const int e = slot ? (item.x & 7) : (item.x >> 3);
  const int tid = threadIdx.x;
  const int w = tid >> 6, l = tid & 63;
  const int wm = w >> 1, wn = w & 1;

  if (tid < 64)
    ids_lds[tid] = (tid < item.z) ? (int)ids[item.y + tid] : -1;
  __syncthreads();

  const int Lb = w * 1024 + l * 16;
  const _Float16* aptr[2];
  const _Float16* bptr[4];
  int ldstA[2], ldstB[4];
#pragma unroll
  for (int i = 0; i < 2; ++i) {
    const int L = i * 4096 + Lb;
    const int row = L >> 7;                       // 0..63
    const int cb = (L & 127) ^ ((row & 7) << 4);
    int t = ids_lds[row]; if (t < 0) t = 0;       // pad rows read token 0
    aptr[i] = xh + (size_t)t * DIM + (cb >> 1);
    ldstA[i] = i * 4096 + w * 1024;
  }
#pragma unroll
  for (int i = 0; i < 4; ++i) {
    const int L = i * 4096 + Lb;
    const int row = L >> 7;                       // 0..127
    const int cb = (L & 127) ^ ((row & 7) << 4);
    bptr[i] = WaT + (size_t)(e * 128 + row) * DIM + (cb >> 1);
    ldstB[i] = i * 4096 + w * 1024;
  }

  f32x4 acc[2][4];
#pragma unroll
  for (int p = 0; p < 2; ++p)
#pragma unroll
    for (int q = 0; q < 4; ++q)
#pragma unroll
      for (int j = 0; j < 4; ++j) acc[p][q][j] = 0.f;

  for (int kt = 0; kt < DIM; kt += 64) {
#pragma unroll
    for (int i = 0; i < 2; ++i)
      gload_lds16(aptr[i] + kt, ldsA + ldstA[i]);
#pragma unroll
    for (int i = 0; i < 4; ++i)
      gload_lds16(bptr[i] + kt, ldsB + ldstB[i]);
    __syncthreads();
#pragma unroll
    for (int kk = 0; kk < 2; ++kk) {
      const int kb = kk * 64 + ((l >> 4) << 4);
      f16x8 af[2], bfr[4];
#pragma unroll
      for (int mf = 0; mf < 2; ++mf) {
        const int r = (wm << 5) + (mf << 4) + (l & 15);
        af[mf] = *(const f16x8*)(ldsA + r * 128 + (kb ^ ((r & 7) << 4)));
      }
#pragma unroll
      for (int nf = 0; nf < 4; ++nf) {
        const int r = (wn << 6) + (nf << 4) + (l & 15);
        bfr[nf] = *(const f16x8*)(ldsB + r * 128 + (kb ^ ((r & 7) << 4)));
      }
#pragma unroll
      for (int mf = 0; mf < 2; ++mf)
#pragma unroll
        for (int nf = 0; nf < 4; ++nf)
          acc[mf][nf] = __builtin_amdgcn_mfma_f32_16x16x32_f16(
              af[mf], bfr[nf], acc[mf][nf], 0, 0, 0);
    }
    __syncthreads();
  }

  // epilogue: m = wm*32 + mf*16 + (l>>4)*4 + j; n = wn*64 + nf*16 + (l&15)
  const int cr = (l >> 4) << 2;
  const int cc = l & 15;
#pragma unroll
  for (int mf = 0; mf < 2; ++mf) {
    const int lr0 = (wm << 5) + (mf << 4) + cr;
#pragma unroll
    for (int j = 0; j < 4; ++j) {
      const int t = ids_lds[lr0 + j];
      if (t < 0) continue;
      const float cs = combine[(size_t)t * 8 + e];
      _Float16* yr = Yc + (size_t)t * 256 + slot * 128 + (wn << 6);
#pragma unroll
      for (int nf = 0; nf < 4; ++nf)
        yr[(nf << 4) + cc] = (_Float16)(acc[mf][nf][j] * cs);
    }
  }
}

// -------------------------------------------------------------- gemm2_pair
// out[t] = Yc[t][0:256] @ [Wb_a; Wb_b] for tokens in this tile's pair bin.
__global__ __launch_bounds__(256) void gemm2_pair_kernel(
    const _Float16* __restrict__ Y, const _Float16* __restrict__ WbT,
    const unsigned short* __restrict__ ids, const int4* __restrict__ items,
    float* __restrict__ out)
{
  __shared__ __align__(16) char lds[32768];
  __shared__ int ids_lds[128];
  char* ldsA = lds;
  char* ldsB = lds + 16384;
  const int4 item = items[blockIdx.y];
  if (item.x < 0) return;                 // block-uniform exit
  const int a = item.x >> 3, b = item.x & 7;
  const int n0 = blockIdx.x * 128;
  const int tid = threadIdx.x;
  const int w = tid >> 6, l = tid & 63;
  const int wm = w >> 1, wn = w & 1;

  if (tid < 128)
    ids_lds[tid] = (tid < item.z) ? (int)ids[item.y + tid] : -1;
  __syncthreads();

  const int Lb = w * 1024 + l * 16;
  const _Float16* aptr[4];
  const _Float16* bptrA[4];
  const _Float16* bptrB[4];
  int ldst[4];
#pragma unroll
  for (int i = 0; i < 4; ++i) {
    const int L = i * 4096 + Lb;
    const int row = L >> 7;
    const int cb = (L & 127) ^ ((row & 7) << 4);
    int t = ids_lds[row]; if (t < 0) t = 0;       // pad rows read token 0
    aptr[i]  = Y + (size_t)t * 256 + (cb >> 1);
    bptrA[i] = WbT + (size_t)(n0 + row) * 1024 + a * 128 + (cb >> 1);
    bptrB[i] = WbT + (size_t)(n0 + row) * 1024 + b * 128 + (cb >> 1);
    ldst[i] = i * 4096 + w * 1024;
  }

  f32x4 acc[4][4];
#pragma unroll
  for (int p = 0; p < 4; ++p)
#pragma unroll
    for (int q = 0; q < 4; ++q)
#pragma unroll
      for (int j = 0; j < 4; ++j) acc[p][q][j] = 0.f;

#pragma unroll
  for (int kt = 0; kt < 4; ++kt) {
#pragma unroll
    for (int i = 0; i < 4; ++i) {
      gload_lds16(aptr[i] + kt * 64, ldsA + ldst[i]);
      const _Float16* bs = (kt < 2) ? (bptrA[i] + kt * 64)
                                    : (bptrB[i] + (kt - 2) * 64);
      gload_lds16(bs, ldsB + ldst[i]);
    }
    __syncthreads();
#pragma unroll
    for (int kk = 0; kk < 2; ++kk) {
      const int kb = kk * 64 + ((l >> 4) << 4);
      f16x8 af[4], bfr[4];
#pragma unroll
      for (int mf = 0; mf < 4; ++mf) {
        const int r = (wm << 6) + (mf << 4) + (l & 15);
        af[mf] = *(const f16x8*)(ldsA + r * 128 + (kb ^ ((r & 7) << 4)));
      }
#pragma unroll
      for (int nf = 0; nf < 4; ++nf) {
        const int r = (wn << 6) + (nf << 4) + (l & 15);
        bfr[nf] = *(const f16x8*)(ldsB + r * 128 + (kb ^ ((r & 7) << 4)));
      }
#pragma unroll
      for (int mf = 0; mf < 4; ++mf)
#pragma unroll
        for (int nf = 0; nf < 4; ++nf)
          acc[mf][nf] = __builtin_amdgcn_mfma_f32_16x16x32_f16(
              af[mf], bfr[nf], acc[mf][nf], 0, 0, 0);
    }
    __syncthreads();
  }

  // epilogue: scatter rows to out[token]
  const int cr = (l >> 4) << 2;
  const int cc = l & 15;
#pragma unroll
  for (int mf = 0; mf < 4; ++mf) {
    const int lr0 = (wm << 6) + (mf << 4) + cr;
#pragma unroll
    for (int j = 0; j < 4; ++j) {
      const int t = ids_lds[lr0 + j];
      if (t < 0) continue;
      float* orow = out + (size_t)t * NOUT + n0;
#pragma unroll
      for (int nf = 0; nf < 4; ++nf)
        orow[(wn << 6) + (nf << 4) + cc] = acc[mf][nf][j];
    }
  }
}

// ------------------------------------------------------------------ launch
extern "C" void kernel_launch(void* const* d_in, const int* in_sizes, int n_in,
                              void* d_out, int out_size, void* d_ws, size_t ws_size,
                              hipStream_t stream) {
  const float* x  = (const float*)d_in[0];   // [4,4096,2048]
  const float* rw = (const float*)d_in[1];   // [2048,8]
  const float* Wa = (const float*)d_in[2];   // [8,2048,128]
  const float* Wb = (const float*)d_in[3];   // [8,128,2048]
  float* out = (float*)d_out;                // [4,4096,2048]

  char* ws = (char*)d_ws;
  // workspace layout (total ~85.5 MB)
  _Float16* xh       = (_Float16*)(ws);                // 67,108,864 [T][2048]
  _Float16* WaT      = (_Float16*)(ws + 67108864);     //  4,194,304 [1024][2048]
  _Float16* WbT      = (_Float16*)(ws + 71303168);     //  4,194,304 [2048][1024]
  float*    combine  = (float*)   (ws + 75497472);     //    524,288 [T][8]
  int*      counts   = (int*)     (ws + 76021760);     //        256 [64]
  int4*     items64  = (int4*)    (ws + 76022016);     //      6,144 [384]
  int4*     items128 = (int4*)    (ws + 76028160);     //      3,072 [192]
  unsigned short* ids16 = (unsigned short*)(ws + 76031232); // 1,048,576 [64][CAP]
  _Float16* Yc       = (_Float16*)(ws + 77079808);     //  8,388,608 [T][256]
  float*    lgpart   = (float*)   (ws + 77079808);     // 2 MB [KSL][T][8], aliases Yc
  float*    ssqpart  = (float*)   (ws + 79177728);     // 256 KB [KSL][T], aliases Yc
  // (lgpart/ssqpart consumed by softmax before gemm1_pair writes Yc)

  // WaT[(e*128+r)][k] = Wa[e][k][r]
  transpose_cast_f16<<<dim3(4, 64, 8), dim3(32, 8), 0, stream>>>(
      Wa, WaT, 2048, 128, 2048, (long)128 * 2048);
  // WbT[n][e*128+r] = Wb[e][r][n]
  transpose_cast_f16<<<dim3(64, 4, 8), dim3(32, 8), 0, stream>>>(
      Wb, WbT, 128, 2048, 1024, 128);

  // also zeroes counts[] (block (0,0)) -- no separate memset node
  logits_fused_kernel<<<dim3(TOKENS / 128, KSL), 256, 0, stream>>>(
      x, rw, lgpart, ssqpart, xh, counts);

  softmax_top2_kernel<<<TOKENS / 256, 256, 0, stream>>>(
      lgpart, ssqpart, combine, counts, ids16);
  make_items_kernel<<<1, 64, 0, stream>>>(counts, items64, items128);

  // Yc[t][slot*128+r] = combine[t][e_slot] * (xh[t] . WaT[e_slot*128+r])
  gemm1_pair_kernel<<<dim3(2, 384), 256, 0, stream>>>(
      xh, WaT, combine, ids16, items64, Yc);
  // out[t] = Yc[t][0:256] @ [Wb_a; Wb_b]
  gemm2_pair_kernel<<<dim3(NOUT / 128, 192), 256, 0, stream>>>(
      Yc, WbT, ids16, items128, out);
}